// Round 12
// baseline (366.640 us; speedup 1.0000x reference)
//
#include <hip/hip_runtime.h>
#include <float.h>
#include <math.h>

#define NB 4            // graphs per batch
#define N0 40962        // nodes per graph at input
#define E0 983088       // total directed edges at layer 0
#define TK_CAP 4096     // candidate capacity for fine top-k select (32 KB LDS)
#define HBITS 12        // coarse histogram bits (4096 bins, LDS-resident)
#define EB 256          // edge-chunk blocks for bucketed CSR build
#define BSHIFT 10       // 1024 dst nodes per bucket
#define BKNODES (1 << BSHIFT)
#define NBKT 161        // ceil(163848 / 1024)
#define NSCAN (NBKT * EB)   // 41216
#define NB0 ((NSCAN + 1023) / 1024)   // 41 scan blocks for bcnt
#define CAP 32          // ELL row capacity for compacted layers (max in-deg ~24)

// ---------------- helpers ----------------

static __device__ __forceinline__ unsigned key32_of(float s) {
    unsigned u = __float_as_uint(s);
    return (u & 0x80000000u) ? ~u : (u | 0x80000000u);
}

static __device__ __forceinline__ unsigned long long key64_of(float s, int li) {
    unsigned u = key32_of(s);
    unsigned low = ~(unsigned)li;   // ties broken by smaller local index
    return ((unsigned long long)u << 32) | (unsigned long long)low;
}

static __device__ __forceinline__ float4 fma4(float s, float4 w, float4 a) {
    a.x = fmaf(s, w.x, a.x); a.y = fmaf(s, w.y, a.y);
    a.z = fmaf(s, w.z, a.z); a.w = fmaf(s, w.w, a.w);
    return a;
}

// exclusive prefix of bsum[0..nb0) into LDS bsumP (first wave; nb0 <= 64)
static __device__ __forceinline__ void bsum_prefix64(const int* __restrict__ bsum,
                                                     int nb0, int* bsumP) {
    if (threadIdx.x < 64) {
        int v = ((int)threadIdx.x < nb0) ? bsum[threadIdx.x] : 0;
        int pp = v;
#pragma unroll
        for (int off = 1; off < 64; off <<= 1) {
            int u = __shfl_up(pp, off, 64);
            if ((int)threadIdx.x >= off) pp += u;
        }
        bsumP[threadIdx.x] = pp - v;   // exclusive
    }
}

// ---------------- L0 bucketed CSR build (R7 known-good; sequential col writes) ----

// A: per-(bucket, block) edge counts via LDS histogram
__global__ void k_bucket_count(const int* __restrict__ ei, int* __restrict__ bcnt) {
    __shared__ unsigned int h[NBKT];
    for (int i = threadIdx.x; i < NBKT; i += 256) h[i] = 0u;
    __syncthreads();
    const int chunk = (E0 + EB - 1) / EB;
    int i0 = blockIdx.x * chunk;
    int i1 = min(E0, i0 + chunk);
    for (int i = i0 + threadIdx.x; i < i1; i += 256)
        atomicAdd(&h[ei[E0 + i] >> BSHIFT], 1u);
    __syncthreads();
    for (int b = threadIdx.x; b < NBKT; b += 256)
        bcnt[b * EB + blockIdx.x] = (int)h[b];
}

// B: scatter (src,dst) pairs into bucketed buffer via LDS cursors (bsum prefix folded in)
__global__ void k_bucket_scatter(const int* __restrict__ ei, const int* __restrict__ boff,
                                 const int* __restrict__ bsum, int2* __restrict__ ebuf) {
    __shared__ int cur[NBKT];
    __shared__ int bsumP[64];
    bsum_prefix64(bsum, NB0, bsumP);
    __syncthreads();
    for (int i = threadIdx.x; i < NBKT; i += 256) {
        int idx = i * EB + blockIdx.x;
        cur[i] = boff[idx] + bsumP[idx >> 10];
    }
    __syncthreads();
    const int chunk = (E0 + EB - 1) / EB;
    int i0 = blockIdx.x * chunk;
    int i1 = min(E0, i0 + chunk);
    for (int i = i0 + threadIdx.x; i < i1; i += 256) {
        int s = ei[i], d = ei[E0 + i];
        int pos = atomicAdd(&cur[d >> BSHIFT], 1);
        ebuf[pos] = make_int2(s, d);
    }
}

// C1: per bucket, per-node in-degrees via LDS histogram -> coalesced degi writes
__global__ void __launch_bounds__(1024) k_bucket_deg(const int2* __restrict__ ebuf,
                                                     const int* __restrict__ boff,
                                                     const int* __restrict__ bsum,
                                                     int* __restrict__ degi, int M) {
    __shared__ unsigned int h[BKNODES];
    __shared__ int bsumP[64];
    bsum_prefix64(bsum, NB0, bsumP);
    int b = blockIdx.x;
    int base = b << BSHIFT;
    int range = min(BKNODES, M - base);
    for (int i = threadIdx.x; i < range; i += 1024) h[i] = 0u;
    __syncthreads();
    int i0 = b * EB;
    int e0 = boff[i0] + bsumP[i0 >> 10];
    int e1 = E0;
    if (b + 1 < NBKT) {
        int i1x = (b + 1) * EB;
        e1 = boff[i1x] + bsumP[i1x >> 10];
    }
    for (int i = e0 + threadIdx.x; i < e1; i += 1024)
        atomicAdd(&h[ebuf[i].y - base], 1u);
    __syncthreads();
    for (int i = threadIdx.x; i < range; i += 1024) degi[base + i] = (int)h[i];
}

// C2: per bucket, place edges into CSR via LDS cursors
__global__ void __launch_bounds__(1024) k_bucket_place(const int2* __restrict__ ebuf,
                                                       const int* __restrict__ boff,
                                                       const int* __restrict__ bsum,
                                                       const int* __restrict__ rowptr,
                                                       int* __restrict__ col, int M) {
    __shared__ int cur[BKNODES];
    __shared__ int bsumP[64];
    bsum_prefix64(bsum, NB0, bsumP);
    int b = blockIdx.x;
    int base = b << BSHIFT;
    int range = min(BKNODES, M - base);
    __syncthreads();
    for (int i = threadIdx.x; i < range; i += 1024) cur[i] = rowptr[base + i];
    int i0 = b * EB;
    int e0 = boff[i0] + bsumP[i0 >> 10];
    int e1 = E0;
    if (b + 1 < NBKT) {
        int i1x = (b + 1) * EB;
        e1 = boff[i1x] + bsumP[i1x >> 10];
    }
    __syncthreads();
    for (int i = e0 + threadIdx.x; i < e1; i += 1024) {
        int2 sd = ebuf[i];
        int pos = atomicAdd(&cur[sd.y - base], 1);
        col[pos] = sd.x;
    }
}

// ---------------- scans (L0 build only) ----------------

__global__ void k_scan1(const int* __restrict__ in, int* __restrict__ out,
                        int* __restrict__ bsum, int M) {
    int t = threadIdx.x;
    int lane = t & 63, wv = t >> 6;
    int base = blockIdx.x * 1024 + t * 4;
    int d0 = (base + 0 < M) ? in[base + 0] : 0;
    int d1 = (base + 1 < M) ? in[base + 1] : 0;
    int d2 = (base + 2 < M) ? in[base + 2] : 0;
    int d3 = (base + 3 < M) ? in[base + 3] : 0;
    int tsum = d0 + d1 + d2 + d3;
    int p = tsum;
#pragma unroll
    for (int off = 1; off < 64; off <<= 1) {
        int u = __shfl_up(p, off, 64);
        if (lane >= off) p += u;
    }
    __shared__ int wsum[4];
    if (lane == 63) wsum[wv] = p;
    __syncthreads();
    int wadd = 0;
    for (int w = 0; w < wv; ++w) wadd += wsum[w];
    int texcl = p + wadd - tsum;
    if (base + 0 < M) out[base + 0] = texcl;
    if (base + 1 < M) out[base + 1] = texcl + d0;
    if (base + 2 < M) out[base + 2] = texcl + d0 + d1;
    if (base + 3 < M) out[base + 3] = texcl + d0 + d1 + d2;
    if (t == 255) bsum[blockIdx.x] = p + wadd;   // block total
}

// stage 2+3 fused: add in-register prefix of bsum; write rowptr[M]; dinv = rsqrt(deg+1)
__global__ void k_scan23(int* __restrict__ rowptr, const int* __restrict__ bsum,
                         const int* __restrict__ degi, float* __restrict__ dinv,
                         int M, int nb) {
    int i = blockIdx.x * 256 + threadIdx.x;
    int c0 = (blockIdx.x * 256) >> 10;   // uniform per block (256 | 1024)
    __shared__ int s_pref, s_tot;
    if (threadIdx.x < 64) {
        int a = 0, tt = 0;
        for (int j = threadIdx.x; j < nb; j += 64) {
            int v = bsum[j];
            tt += v;
            if (j < c0) a += v;
        }
#pragma unroll
        for (int off = 32; off > 0; off >>= 1) {
            a += __shfl_xor(a, off, 64);
            tt += __shfl_xor(tt, off, 64);
        }
        if (threadIdx.x == 0) { s_pref = a; s_tot = tt; }
    }
    __syncthreads();
    if (i < M) {
        rowptr[i] += s_pref;
        dinv[i] = rsqrtf((float)degi[i] + 1.0f);
    }
    if (i == 0) rowptr[M] = s_tot;
}

// ---------------- fused graph compaction (ELL output) ----------------

template <bool ELLIN>
__global__ void k_compact(const int* __restrict__ remap, const int* __restrict__ rpO,
                          const int* __restrict__ colO, const int* __restrict__ degO,
                          int* __restrict__ colN, int* __restrict__ degN,
                          float* __restrict__ dinvN, int Mold) {
    int m = blockIdx.x * blockDim.x + threadIdx.x;
    if (m >= Mold) return;
    int nd = remap[m];
    if (nd < 0) return;
    int j0, j1;
    if (ELLIN) { j0 = m * CAP; j1 = j0 + degO[m]; }
    else       { j0 = rpO[m];  j1 = rpO[m + 1]; }
    int w = nd * CAP;
    int c = 0;
    for (int j = j0; j < j1; ++j) {
        int rs = remap[colO[j]];
        if (rs >= 0) { colN[w + c] = rs; ++c; }
    }
    degN[nd] = c;
    dinvN[nd] = rsqrtf((float)c + 1.0f);
}

// ---------------- fused gather + dense layer ----------------
// Phase 1: aggregate the block's RPB rows into an LDS tile (CSR at L0, ELL after).
// Phase 2: mm + bias + relu + score from LDS. L0CSR: spill tile to axg (source for
// the select-recompute path). WY: write y (L1..L3 copy path).
template <int FI, int FO, bool WY, bool L0CSR>
__global__ void __launch_bounds__(256) k_gmm(
        const float* __restrict__ x,
        const int* __restrict__ rowptr, const int* __restrict__ colC,
        const int* __restrict__ colE, const int* __restrict__ deg,
        const float* __restrict__ dinv,
        const float* __restrict__ W, const float* __restrict__ bias,
        const float* __restrict__ pvec,
        float* __restrict__ y, float* __restrict__ score, float* __restrict__ axg,
        int M, int n, int npad) {
    constexpr int Q = FO / 4;            // lanes per row-quad
    constexpr int RPB = (256 / Q) * 4;   // rows per block (128/64/32/32)
    constexpr int STR = FI + 4;          // padded LDS row stride (16B-aligned)
    constexpr int ELEMS = RPB * FI;
    __shared__ float axs[RPB * STR];
    int row0 = blockIdx.x * RPB;

    // ---- phase 1: aggregation into LDS ----
    for (int idx = threadIdx.x; idx < ELEMS; idx += 256) {
        int rl = idx / FI, f = idx - rl * FI;
        int row = row0 + rl;
        if (row < M) {
            float dd = dinv[row];
            float invdeg = dd * dd;
            float acc = x[(size_t)row * FI + f] * invdeg;
            if (L0CSR) {
                int j0 = rowptr[row], j1 = rowptr[row + 1];
                for (int j = j0; j < j1; ++j) {
                    int s = colC[j];
                    float nrm = dd * dinv[s];
                    acc = fmaf(x[(size_t)s * FI + f], nrm, acc);
                }
            } else {
                int dg = min(deg[row], CAP);
                const int* cr = colE + (size_t)row * CAP;
                for (int j = 0; j < dg; ++j) {
                    int s = cr[j];
                    float nrm = dd * dinv[s];
                    acc = fmaf(x[(size_t)s * FI + f], nrm, acc);
                }
            }
            axs[rl * STR + f] = acc;
        }
    }
    __syncthreads();
    if (L0CSR) {   // spill tile to global ax for the select-recompute path
        for (int idx = threadIdx.x; idx < ELEMS; idx += 256) {
            int rl = idx / FI, f = idx - rl * FI;
            int row = row0 + rl;
            if (row < M) axg[(size_t)row * FI + f] = axs[rl * STR + f];
        }
    }

    // ---- phase 2: mm body, row-quad from LDS ----
    int q = threadIdx.x % Q;
    int lrow = (threadIdx.x / Q) * 4;
    int row = row0 + lrow;
    if (row >= M) return;   // M divisible by 4 -> quads never straddle M
    const float4* x0 = (const float4*)(axs + (lrow + 0) * STR);
    const float4* x1 = (const float4*)(axs + (lrow + 1) * STR);
    const float4* x2 = (const float4*)(axs + (lrow + 2) * STR);
    const float4* x3 = (const float4*)(axs + (lrow + 3) * STR);
    const float4* W4 = (const float4*)W;
    float4 a0 = {0.f, 0.f, 0.f, 0.f}, a1 = {0.f, 0.f, 0.f, 0.f};
    float4 a2 = {0.f, 0.f, 0.f, 0.f}, a3 = {0.f, 0.f, 0.f, 0.f};
#pragma unroll 2
    for (int c = 0; c < FI / 4; ++c) {
        float4 v0 = x0[c], v1 = x1[c], v2 = x2[c], v3 = x3[c];
        const float4* wr = W4 + (size_t)(c * 4) * Q + q;
        float4 w;
        w = wr[0 * Q];
        a0 = fma4(v0.x, w, a0); a1 = fma4(v1.x, w, a1);
        a2 = fma4(v2.x, w, a2); a3 = fma4(v3.x, w, a3);
        w = wr[1 * Q];
        a0 = fma4(v0.y, w, a0); a1 = fma4(v1.y, w, a1);
        a2 = fma4(v2.y, w, a2); a3 = fma4(v3.y, w, a3);
        w = wr[2 * Q];
        a0 = fma4(v0.z, w, a0); a1 = fma4(v1.z, w, a1);
        a2 = fma4(v2.z, w, a2); a3 = fma4(v3.z, w, a3);
        w = wr[3 * Q];
        a0 = fma4(v0.w, w, a0); a1 = fma4(v1.w, w, a1);
        a2 = fma4(v2.w, w, a2); a3 = fma4(v3.w, w, a3);
    }
    float4 b4 = ((const float4*)bias)[q];
    float4 o0, o1, o2, o3;
    o0.x = fmaxf(a0.x + b4.x, 0.f); o0.y = fmaxf(a0.y + b4.y, 0.f);
    o0.z = fmaxf(a0.z + b4.z, 0.f); o0.w = fmaxf(a0.w + b4.w, 0.f);
    o1.x = fmaxf(a1.x + b4.x, 0.f); o1.y = fmaxf(a1.y + b4.y, 0.f);
    o1.z = fmaxf(a1.z + b4.z, 0.f); o1.w = fmaxf(a1.w + b4.w, 0.f);
    o2.x = fmaxf(a2.x + b4.x, 0.f); o2.y = fmaxf(a2.y + b4.y, 0.f);
    o2.z = fmaxf(a2.z + b4.z, 0.f); o2.w = fmaxf(a2.w + b4.w, 0.f);
    o3.x = fmaxf(a3.x + b4.x, 0.f); o3.y = fmaxf(a3.y + b4.y, 0.f);
    o3.z = fmaxf(a3.z + b4.z, 0.f); o3.w = fmaxf(a3.w + b4.w, 0.f);
    if (WY) {
        ((float4*)(y + (size_t)(row + 0) * FO))[q] = o0;
        ((float4*)(y + (size_t)(row + 1) * FO))[q] = o1;
        ((float4*)(y + (size_t)(row + 2) * FO))[q] = o2;
        ((float4*)(y + (size_t)(row + 3) * FO))[q] = o3;
    }
    float4 p4 = ((const float4*)pvec)[q];
    float d0 = o0.x * p4.x + o0.y * p4.y + o0.z * p4.z + o0.w * p4.w;
    float d1 = o1.x * p4.x + o1.y * p4.y + o1.z * p4.z + o1.w * p4.w;
    float d2 = o2.x * p4.x + o2.y * p4.y + o2.z * p4.z + o2.w * p4.w;
    float d3 = o3.x * p4.x + o3.y * p4.y + o3.z * p4.z + o3.w * p4.w;
    float pn = p4.x * p4.x + p4.y * p4.y + p4.z * p4.z + p4.w * p4.w;
#pragma unroll
    for (int off = Q / 2; off > 0; off >>= 1) {
        d0 += __shfl_xor(d0, off, 64);
        d1 += __shfl_xor(d1, off, 64);
        d2 += __shfl_xor(d2, off, 64);
        d3 += __shfl_xor(d3, off, 64);
        pn += __shfl_xor(pn, off, 64);
    }
    if (q == 0) {
        float inv = rsqrtf(pn);
        float s[4] = {d0 * inv, d1 * inv, d2 * inv, d3 * inv};
#pragma unroll
        for (int j = 0; j < 4; ++j) {
            int rj = row + j;
            int b = rj / n;
            int i = rj - b * n;
            score[(size_t)b * npad + i] = s[j];
        }
    }
}

// ---------------- top-k (coarse hist fused in; R6 fine-radix structure) ----------

__global__ void __launch_bounds__(1024) k_topk_fine(
        const float* __restrict__ score,
        unsigned long long* __restrict__ T64, int* __restrict__ cnt,
        int n, int npad, int k) {
    int b = blockIdx.x;
    int t = threadIdx.x;
    int lane = t & 63;
    int wv = t >> 6;                 // 16 waves
    const float* sc = score + (size_t)b * npad;
    __shared__ unsigned int hist12s[1 << HBITS];   // 16 KB, block-local coarse hist
    __shared__ unsigned long long cand[TK_CAP];    // 32 KB
    __shared__ unsigned int hist[256];
    __shared__ int wsum16[16];
    __shared__ int s_P12, s_r, s_c, s_rr, s_done, s_cc, s_m;
    __shared__ unsigned s_low;
    __shared__ unsigned long long s_prefix;

    // ---- build 4096-bin coarse histogram in LDS ----
    for (int i = t; i < (1 << HBITS); i += 1024) hist12s[i] = 0u;
    __syncthreads();
    for (int i = t << 2; i < n; i += 4096) {
        float4 v = *(const float4*)(sc + i);   // 16B-aligned (npad%4==0)
        atomicAdd(&hist12s[key32_of(v.x) >> (32 - HBITS)], 1u);
        if (i + 1 < n) atomicAdd(&hist12s[key32_of(v.y) >> (32 - HBITS)], 1u);
        if (i + 2 < n) atomicAdd(&hist12s[key32_of(v.z) >> (32 - HBITS)], 1u);
        if (i + 3 < n) atomicAdd(&hist12s[key32_of(v.w) >> (32 - HBITS)], 1u);
    }
    __syncthreads();

    // ---- coarse phase: suffix scan of 4096 bins (4 bins/thread) ----
    uint4 g4 = ((const uint4*)hist12s)[t];
    int sum = (int)(g4.x + g4.y + g4.z + g4.w);
    int ssum = sum;
#pragma unroll
    for (int off = 1; off < 64; off <<= 1) {
        int v = __shfl_down(ssum, off, 64);
        if (lane + off < 64) ssum += v;
    }
    if (lane == 0) wsum16[wv] = ssum;
    __syncthreads();
    {
        int hi = 0;
        for (int w = wv + 1; w < 16; ++w) hi += wsum16[w];
        int suffIncl = ssum + hi;
        int cumAbove = suffIncl - sum;
        if (cumAbove < k && suffIncl >= k) {      // unique thread owns threshold chunk
            unsigned bv0 = g4.x, bv1 = g4.y, bv2 = g4.z, bv3 = g4.w;
            int base = t << 2;
            int cum = cumAbove;
            int cb;
            cb = (int)bv3; cum += cb;
            if (cum >= k) { s_P12 = base + 3; s_r = k - (cum - cb); s_c = cb; }
            else {
                cb = (int)bv2; cum += cb;
                if (cum >= k) { s_P12 = base + 2; s_r = k - (cum - cb); s_c = cb; }
                else {
                    cb = (int)bv1; cum += cb;
                    if (cum >= k) { s_P12 = base + 1; s_r = k - (cum - cb); s_c = cb; }
                    else {
                        cb = (int)bv0; cum += cb;
                        s_P12 = base; s_r = k - (cum - cb); s_c = cb;
                    }
                }
            }
        }
    }
    if (t == 0) s_cc = 0;
    __syncthreads();
    int P12 = s_P12, r = s_r, c = s_c;

    // ---- candidate collection: float4 over padded score; matches are rare ----
    if (c <= TK_CAP) {
        for (int i = t << 2; i < n; i += 4096) {
            float4 v = *(const float4*)(sc + i);
            unsigned u0 = key32_of(v.x), u1 = key32_of(v.y);
            unsigned u2 = key32_of(v.z), u3 = key32_of(v.w);
            if ((int)(u0 >> (32 - HBITS)) == P12) {
                int pos = atomicAdd(&s_cc, 1);
                cand[pos] = ((unsigned long long)u0 << 32) | (unsigned long long)(~(unsigned)(i + 0));
            }
            if (i + 1 < n && (int)(u1 >> (32 - HBITS)) == P12) {
                int pos = atomicAdd(&s_cc, 1);
                cand[pos] = ((unsigned long long)u1 << 32) | (unsigned long long)(~(unsigned)(i + 1));
            }
            if (i + 2 < n && (int)(u2 >> (32 - HBITS)) == P12) {
                int pos = atomicAdd(&s_cc, 1);
                cand[pos] = ((unsigned long long)u2 << 32) | (unsigned long long)(~(unsigned)(i + 2));
            }
            if (i + 3 < n && (int)(u3 >> (32 - HBITS)) == P12) {
                int pos = atomicAdd(&s_cc, 1);
                cand[pos] = ((unsigned long long)u3 << 32) | (unsigned long long)(~(unsigned)(i + 3));
            }
        }
    }
    if (t == 0) {
        s_prefix = ((unsigned long long)(unsigned)P12) << (64 - HBITS);
        s_rr = r;
        s_done = 0;
        s_m = 0;
        s_low = 0u;
    }
    if (t < 256) hist[t] = 0u;
    __syncthreads();

    if (c <= TK_CAP) {
        // ---- in-LDS fine radix over candidates; 2 barriers/pass ----
        int cc = s_cc;
        const int shf[7] = {44, 36, 32, 24, 16, 8, 0};
        const int wid[7] = {8, 8, 4, 8, 8, 8, 8};
        for (int pi = 0; pi < 7; ++pi) {
            if (s_done) break;
            if (pi == 3 && s_m == 1) {
                unsigned long long pref = s_prefix;
                for (int i = t; i < cc; i += 1024) {
                    unsigned long long key = cand[i];
                    if ((key >> 32) == (pref >> 32)) s_low = (unsigned)key;
                }
                __syncthreads();
                if (t == 0) { s_prefix = pref | (unsigned long long)s_low; s_done = 1; }
                __syncthreads();
                break;
            }
            int shift = shf[pi], wd = wid[pi];
            int nbins = 1 << wd;
            unsigned mask = (unsigned)nbins - 1u;
            unsigned long long prefix = s_prefix;
            int hs = shift + wd;
            for (int i = t; i < cc; i += 1024) {
                unsigned long long key = cand[i];
                if ((key >> hs) == (prefix >> hs))
                    atomicAdd(&hist[(unsigned)(key >> shift) & mask], 1u);
            }
            __syncthreads();
            if (t < 64) {
                int bpl = (nbins + 63) >> 6;
                int b0 = t * bpl;
                int cl[4];
                int lsum = 0;
#pragma unroll
                for (int j = 0; j < 4; ++j) {
                    int bi = b0 + j;
                    int v = (j < bpl && bi < nbins) ? (int)hist[bi] : 0;
                    cl[j] = v;
                    lsum += v;
                }
                int suf = lsum;
#pragma unroll
                for (int off = 1; off < 64; off <<= 1) {
                    int v = __shfl_down(suf, off, 64);
                    if (t + off < 64) suf += v;
                }
                int rr = s_rr;
                int run = suf - lsum;
                for (int j = bpl - 1; j >= 0; --j) {
                    int cb = cl[j];
                    int suffIncl = run + cb;
                    if (run < rr && rr <= suffIncl) {
                        s_prefix = prefix | ((unsigned long long)(b0 + j) << shift);
                        s_rr = rr - run;
                        s_m = cb;
                        if (rr == suffIncl) s_done = 1;
                    }
                    run = suffIncl;
                }
#pragma unroll
                for (int j = 0; j < 4; ++j)
                    if (j < bpl && b0 + j < nbins) hist[b0 + j] = 0u;
            }
            __syncthreads();
        }
    } else {
        // ---- fallback: full-rescan multi-wave path ----
        const int shifts[7] = {44, 36, 28, 20, 12, 4, 0};
        const int widths[7] = {8, 8, 8, 8, 8, 8, 4};
        for (int pi = 0; pi < 7; ++pi) {
            if (s_done) break;
            int shift = shifts[pi], wd = widths[pi];
            int nbins = 1 << wd;
            unsigned mask = (unsigned)nbins - 1u;
            if (t < 256) hist[t] = 0u;
            __syncthreads();
            unsigned long long prefix = s_prefix;
            int rr = s_rr;
            int hs = shift + wd;
            for (int i = t; i < n; i += 1024) {
                unsigned long long key = key64_of(sc[i], i);
                if ((key >> hs) == (prefix >> hs))
                    atomicAdd(&hist[(unsigned)(key >> shift) & mask], 1u);
            }
            __syncthreads();
            int cb = 0, suff = 0;
            if (t < 256) {
                cb = (t < nbins) ? (int)hist[t] : 0;
                suff = cb;
#pragma unroll
                for (int off = 1; off < 64; off <<= 1) {
                    int v = __shfl_down(suff, off, 64);
                    if (lane + off < 64) suff += v;
                }
                if (lane == 0) wsum16[wv] = suff;
            }
            __syncthreads();
            if (t < nbins) {
                int nw = (nbins + 63) >> 6;
                int hi = 0;
                for (int w = wv + 1; w < nw; ++w) hi += wsum16[w];
                int suffIncl = suff + hi;
                int suffExcl = suffIncl - cb;
                if (suffExcl < rr && rr <= suffIncl) {
                    s_prefix = prefix | ((unsigned long long)t << shift);
                    s_rr = rr - suffExcl;
                    if (rr == suffIncl) s_done = 1;
                }
            }
            __syncthreads();
        }
    }
    if (t == 0) { T64[b] = s_prefix; cnt[b] = 0; }
}

// ---------------- select (L0: recompute y for kept rows from ax) ----------------
template <int FI, int FO>
__global__ void k_select_rc(const float* __restrict__ score, const float* __restrict__ ax,
                            const float* __restrict__ W, const float* __restrict__ bias,
                            const unsigned long long* __restrict__ T64, int* __restrict__ cnt,
                            int* __restrict__ remap, float* __restrict__ xout,
                            int n, int npad, int k) {
    constexpr int Q = FO / 4;
    constexpr int RPI = 256 / Q;
    int b = blockIdx.y;
    int i = blockIdx.x * 256 + threadIdx.x;
    bool keep = false;
    float s = 0.f;
    if (i < n) {
        s = score[(size_t)b * npad + i];
        keep = key64_of(s, i) >= T64[b];
    }
    unsigned long long mask = __ballot(keep);
    int lane = threadIdx.x & 63;
    int wv = threadIdx.x >> 6;
    int lp = __popcll(mask & ((1ULL << lane) - 1ULL));
    __shared__ int woff[4];
    __shared__ int blockBase, nkept;
    __shared__ int km[256];
    __shared__ float ks[256];
    if (lane == 0) woff[wv] = __popcll(mask);
    __syncthreads();
    if (threadIdx.x == 0) {
        int t0 = woff[0], t1 = woff[1], t2 = woff[2], t3 = woff[3];
        woff[0] = 0; woff[1] = t0; woff[2] = t0 + t1; woff[3] = t0 + t1 + t2;
        int tot = t0 + t1 + t2 + t3;
        nkept = tot;
        blockBase = atomicAdd(&cnt[b], tot);
    }
    __syncthreads();
    int bb = blockBase;
    if (i < n) {
        if (keep) {
            int idx = woff[wv] + lp;
            km[idx] = i;
            ks[idx] = tanhf(s);
            remap[b * n + i] = b * k + bb + idx;
        } else {
            remap[b * n + i] = -1;
        }
    }
    __syncthreads();
    int q = threadIdx.x % Q;
    int rslot = threadIdx.x / Q;
    const float4* W4 = (const float4*)W;
    float4 b4 = ((const float4*)bias)[q];
    float4* x4 = (float4*)xout + ((size_t)b * k + bb) * Q;
    int nk = nkept;
    for (int r0 = rslot; r0 < nk; r0 += RPI) {
        int gi = km[r0];
        const float4* xr = (const float4*)(ax + ((size_t)b * n + gi) * FI);
        float4 a0 = {0.f, 0.f, 0.f, 0.f};
#pragma unroll 2
        for (int c = 0; c < FI / 4; ++c) {
            float4 v0 = xr[c];
            const float4* wr = W4 + (size_t)(c * 4) * Q + q;
            a0 = fma4(v0.x, wr[0 * Q], a0);
            a0 = fma4(v0.y, wr[1 * Q], a0);
            a0 = fma4(v0.z, wr[2 * Q], a0);
            a0 = fma4(v0.w, wr[3 * Q], a0);
        }
        float4 o;
        o.x = fmaxf(a0.x + b4.x, 0.f);
        o.y = fmaxf(a0.y + b4.y, 0.f);
        o.z = fmaxf(a0.z + b4.z, 0.f);
        o.w = fmaxf(a0.w + b4.w, 0.f);
        float sc_ = ks[r0];
        float4 ov;
        ov.x = o.x * sc_; ov.y = o.y * sc_; ov.z = o.z * sc_; ov.w = o.w * sc_;
        x4[(size_t)r0 * Q + q] = ov;
    }
}

// select copy-path (L1..L2): coalesced float4 row copy of kept rows from y
template <int FO>
__global__ void k_select_cp(const float* __restrict__ score, const float* __restrict__ y,
                            const unsigned long long* __restrict__ T64, int* __restrict__ cnt,
                            int* __restrict__ remap, float* __restrict__ xout,
                            int n, int npad, int k) {
    constexpr int Fo4 = FO / 4;
    int b = blockIdx.y;
    int i = blockIdx.x * 256 + threadIdx.x;
    bool keep = false;
    float s = 0.f;
    if (i < n) {
        s = score[(size_t)b * npad + i];
        keep = key64_of(s, i) >= T64[b];
    }
    unsigned long long mask = __ballot(keep);
    int lane = threadIdx.x & 63;
    int wv = threadIdx.x >> 6;
    int lp = __popcll(mask & ((1ULL << lane) - 1ULL));
    __shared__ int woff[4];
    __shared__ int blockBase, nkept;
    __shared__ int km[256];
    __shared__ float ks[256];
    if (lane == 0) woff[wv] = __popcll(mask);
    __syncthreads();
    if (threadIdx.x == 0) {
        int t0 = woff[0], t1 = woff[1], t2 = woff[2], t3 = woff[3];
        woff[0] = 0; woff[1] = t0; woff[2] = t0 + t1; woff[3] = t0 + t1 + t2;
        int tot = t0 + t1 + t2 + t3;
        nkept = tot;
        blockBase = atomicAdd(&cnt[b], tot);
    }
    __syncthreads();
    int bb = blockBase;
    if (i < n) {
        if (keep) {
            int idx = woff[wv] + lp;
            km[idx] = i;
            ks[idx] = tanhf(s);
            remap[b * n + i] = b * k + bb + idx;
        } else {
            remap[b * n + i] = -1;
        }
    }
    __syncthreads();
    int tot4 = nkept * Fo4;
    const float4* y4 = (const float4*)y + (size_t)b * n * Fo4;
    float4* x4 = (float4*)xout + ((size_t)b * k + bb) * Fo4;
    for (int j = threadIdx.x; j < tot4; j += 256) {
        int r = j / Fo4;
        int cc = j & (Fo4 - 1);
        float4 v = y4[(size_t)km[r] * Fo4 + cc];
        float sc_ = ks[r];
        float4 o;
        o.x = v.x * sc_; o.y = v.y * sc_; o.z = v.z * sc_; o.w = v.w * sc_;
        x4[(size_t)r * Fo4 + cc] = o;
    }
}

// L3 select + pooling fused: pool (max/sum) the block's kept scaled rows directly
// into per-block partials. No xout / remap at L3 (nothing consumes them).
__global__ void k_select_cp_pool(const float* __restrict__ score, const float* __restrict__ y,
                                 const unsigned long long* __restrict__ T64,
                                 float* __restrict__ pmax, float* __restrict__ psum,
                                 int n, int npad, int nch) {
    int b = blockIdx.y;
    int i = blockIdx.x * 256 + threadIdx.x;
    bool keep = false;
    float s = 0.f;
    if (i < n) {
        s = score[(size_t)b * npad + i];
        keep = key64_of(s, i) >= T64[b];
    }
    unsigned long long mask = __ballot(keep);
    int lane = threadIdx.x & 63;
    int wv = threadIdx.x >> 6;
    int lp = __popcll(mask & ((1ULL << lane) - 1ULL));
    __shared__ int woff[4];
    __shared__ int nkept;
    __shared__ int km[256];
    __shared__ float ks[256];
    __shared__ float4 redm[256];
    __shared__ float4 reds[256];
    if (lane == 0) woff[wv] = __popcll(mask);
    __syncthreads();
    if (threadIdx.x == 0) {
        int t0 = woff[0], t1 = woff[1], t2 = woff[2], t3 = woff[3];
        woff[0] = 0; woff[1] = t0; woff[2] = t0 + t1; woff[3] = t0 + t1 + t2;
        nkept = t0 + t1 + t2 + t3;
    }
    __syncthreads();
    if (i < n && keep) {
        int idx = woff[wv] + lp;
        km[idx] = i;
        ks[idx] = tanhf(s);
    }
    __syncthreads();
    // pooled accumulation: thread covers fixed float4 column cc = tid&31 (256%32==0)
    int cc = threadIdx.x & 31;
    float4 mx = {-FLT_MAX, -FLT_MAX, -FLT_MAX, -FLT_MAX};
    float4 sm = {0.f, 0.f, 0.f, 0.f};
    int tot4 = nkept * 32;
    const float4* y4 = (const float4*)y + (size_t)b * n * 32;
    for (int j = threadIdx.x; j < tot4; j += 256) {
        int r = j >> 5;
        float4 v = y4[(size_t)km[r] * 32 + cc];
        float sc_ = ks[r];
        v.x *= sc_; v.y *= sc_; v.z *= sc_; v.w *= sc_;
        mx.x = fmaxf(mx.x, v.x); mx.y = fmaxf(mx.y, v.y);
        mx.z = fmaxf(mx.z, v.z); mx.w = fmaxf(mx.w, v.w);
        sm.x += v.x; sm.y += v.y; sm.z += v.z; sm.w += v.w;
    }
    redm[threadIdx.x] = mx;
    reds[threadIdx.x] = sm;
    __syncthreads();
    if (threadIdx.x < 32) {
        float4 m = redm[threadIdx.x];
        float4 ss = reds[threadIdx.x];
        for (int g = 1; g < 8; ++g) {
            float4 m2 = redm[threadIdx.x + 32 * g];
            float4 s2 = reds[threadIdx.x + 32 * g];
            m.x = fmaxf(m.x, m2.x); m.y = fmaxf(m.y, m2.y);
            m.z = fmaxf(m.z, m2.z); m.w = fmaxf(m.w, m2.w);
            ss.x += s2.x; ss.y += s2.y; ss.z += s2.z; ss.w += s2.w;
        }
        size_t o = ((size_t)b * nch + blockIdx.x) * 32 + threadIdx.x;
        ((float4*)pmax)[o] = m;
        ((float4*)psum)[o] = ss;
    }
}

// final: one block (128 threads) per graph: combine partials + metadata conv + fc + fc2
__global__ void k_final2(const float* __restrict__ pmax, const float* __restrict__ psum,
                         const float* __restrict__ metadata,
                         const float* __restrict__ convm_w, const float* __restrict__ convm_b,
                         const float* __restrict__ fc_w, const float* __restrict__ fc_b,
                         const float* __restrict__ fc2_w, const float* __restrict__ fc2_b,
                         float* __restrict__ out, int K3, int nch) {
    int b = blockIdx.x;
    int f = threadIdx.x;   // 0..127
    __shared__ float xc[260];
    __shared__ float red[128];
    float mx = -FLT_MAX, sm = 0.f;
    for (int c = 0; c < nch; ++c) {
        int o = (b * nch + c) * 128 + f;
        mx = fmaxf(mx, pmax[o]);
        sm += psum[o];
    }
    xc[f] = mx;
    xc[128 + f] = sm / (float)K3;
    if (f < 4) {
        float mv = metadata[b] * convm_w[f] + convm_b[f];
        xc[256 + f] = mv > 0.f ? mv : 0.f;
    }
    __syncthreads();
    float acc = fc_b[f];
    for (int i = 0; i < 260; ++i) acc = fmaf(xc[i], fc_w[i * 128 + f], acc);
    acc = acc > 0.f ? acc : 0.f;
    red[f] = acc * fc2_w[f];
    __syncthreads();
    for (int s2 = 64; s2 > 0; s2 >>= 1) {
        if (f < s2) red[f] += red[f + s2];
        __syncthreads();
    }
    if (f == 0) out[b] = red[0] + fc2_b[0];
}

// ---------------- launch ----------------

extern "C" void kernel_launch(void* const* d_in, const int* in_sizes, int n_in,
                              void* d_out, int out_size, void* d_ws, size_t ws_size,
                              hipStream_t stream) {
    const float* x0       = (const float*)d_in[0];
    const int*   ei       = (const int*)d_in[1];
    const float* metadata = (const float*)d_in[2];
    const float* W[4]  = {(const float*)d_in[3], (const float*)d_in[6],
                          (const float*)d_in[9], (const float*)d_in[12]};
    const float* bs[4] = {(const float*)d_in[4], (const float*)d_in[7],
                          (const float*)d_in[10], (const float*)d_in[13]};
    const float* pv[4] = {(const float*)d_in[5], (const float*)d_in[8],
                          (const float*)d_in[11], (const float*)d_in[14]};
    const float* convm_w = (const float*)d_in[15];
    const float* convm_b = (const float*)d_in[16];
    const float* fc_w    = (const float*)d_in[17];
    const float* fc_b    = (const float*)d_in[18];
    const float* fc2_w   = (const float*)d_in[19];
    const float* fc2_b   = (const float*)d_in[20];

    // workspace bump allocation
    const size_t AXMAX = 655392;           // L0 ax spill: 163848*4
    const size_t YMAX  = 5243392;          // max M*FO (L1: 81924*64)
    const size_t XMAX  = 2621952;
    const size_t MMAX  = NB * (size_t)N0;  // 163848
    const int    NCH3  = (5121 + 255) / 256;   // 21 pooling partials per graph

    char* p = (char*)d_ws;
    size_t off = 0;
    auto alloc = [&](size_t bytes) -> char* {
        char* r = p + off;
        off = (off + bytes + 255) & ~(size_t)255;
        return r;
    };
    float* ax     = (float*)alloc(AXMAX * 4);         // L0 only (select_rc source)
    float* y      = (float*)alloc(YMAX * 4);          // L1..L3 copy path
    float* xb0    = (float*)alloc(XMAX * 4);
    float* xb1    = (float*)alloc(XMAX * 4);
    float* dinv   = (float*)alloc(MMAX * 4);
    float* score  = (float*)alloc((MMAX + 64) * 4);   // padded per-graph stride
    int*   remap  = (int*)alloc(MMAX * 4);
    int*   degi   = (int*)alloc(MMAX * 4);            // L0 build degrees
    int*   degEA  = (int*)alloc(81924 * 4);           // ELL degrees ping
    int*   degEB  = (int*)alloc(40964 * 4);           // ELL degrees pong
    int*   rowptrA= (int*)alloc((MMAX + 1) * 4);
    int*   colA   = (int*)alloc(E0 * 4);
    int*   colEA  = (int*)alloc((size_t)81924 * CAP * 4);   // 10.5 MB
    int*   colEB  = (int*)alloc((size_t)40964 * CAP * 4);   // 5.25 MB
    int2*  ebuf   = (int2*)alloc((size_t)E0 * 8);
    int*   bcnt   = (int*)alloc(NSCAN * 4);
    int*   boff   = (int*)alloc(NSCAN * 4);
    int*   bsumA  = (int*)alloc(260 * 4);
    int*   bsumB  = (int*)alloc(260 * 4);
    float* pmax   = (float*)alloc((size_t)NB * NCH3 * 128 * 4);
    float* psum   = (float*)alloc((size_t)NB * NCH3 * 128 * 4);
    unsigned long long* T64 = (unsigned long long*)alloc(NB * 8);
    int*   cnt    = (int*)alloc(NB * 4);
    (void)ws_size; (void)n_in; (void)in_sizes; (void)out_size;

    const int Kk[4] = {20481, 10241, 5121, 2561};
    const int TB = 256;

    // ---- L0 CSR build: bucketed, bsum prefixes folded into consumers ----
    int M = NB * N0;
    {
        k_bucket_count<<<EB, 256, 0, stream>>>(ei, bcnt);
        k_scan1<<<NB0, 256, 0, stream>>>(bcnt, boff, bsumA, NSCAN);
        k_bucket_scatter<<<EB, 256, 0, stream>>>(ei, boff, bsumA, ebuf);
        k_bucket_deg<<<NBKT, 1024, 0, stream>>>(ebuf, boff, bsumA, degi, M);
        int nb = (M + 1023) / 1024;
        k_scan1<<<nb, 256, 0, stream>>>(degi, rowptrA, bsumB, M);
        k_scan23<<<(M + 255) / 256, 256, 0, stream>>>(rowptrA, bsumB, degi, dinv, M, nb);
        k_bucket_place<<<NBKT, 1024, 0, stream>>>(ebuf, boff, bsumA, rowptrA, colA, M);
    }

    const float* xin = x0;
    float* xbufs[2] = {xb0, xb1};

    for (int L = 0; L < 4; ++L) {
        int n = M / NB, kk = Kk[L];
        int npad = (n + 3) & ~3;

        // ---- fused gather + matmul + bias + relu + score ----
        if (L == 0) {
            int nbk = (M + 127) / 128;   // RPB=128
            k_gmm<4, 32, false, true><<<nbk, 256, 0, stream>>>(
                xin, rowptrA, colA, nullptr, nullptr, dinv,
                W[L], bs[L], pv[L], y, score, ax, M, n, npad);
        } else if (L == 1) {
            int nbk = (M + 63) / 64;     // RPB=64
            k_gmm<32, 64, true, false><<<nbk, 256, 0, stream>>>(
                xin, nullptr, nullptr, colEA, degEA, dinv,
                W[L], bs[L], pv[L], y, score, nullptr, M, n, npad);
        } else if (L == 2) {
            int nbk = (M + 31) / 32;     // RPB=32
            k_gmm<64, 128, true, false><<<nbk, 256, 0, stream>>>(
                xin, nullptr, nullptr, colEB, degEB, dinv,
                W[L], bs[L], pv[L], y, score, nullptr, M, n, npad);
        } else {
            int nbk = (M + 31) / 32;     // RPB=32
            k_gmm<128, 128, true, false><<<nbk, 256, 0, stream>>>(
                xin, nullptr, nullptr, colEA, degEA, dinv,
                W[L], bs[L], pv[L], y, score, nullptr, M, n, npad);
        }

        // ---- top-k (coarse hist fused) ----
        k_topk_fine<<<NB, 1024, 0, stream>>>(score, T64, cnt, n, npad, kk);
        float* xout = xbufs[L & 1];
        dim3 gsel((n + 255) / 256, NB);
        if (L == 0)
            k_select_rc<4, 32><<<gsel, 256, 0, stream>>>(score, ax, W[L], bs[L], T64, cnt,
                                                         remap, xout, n, npad, kk);
        else if (L == 1)
            k_select_cp<64><<<gsel, 256, 0, stream>>>(score, y, T64, cnt,
                                                      remap, xout, n, npad, kk);
        else if (L == 2)
            k_select_cp<128><<<gsel, 256, 0, stream>>>(score, y, T64, cnt,
                                                       remap, xout, n, npad, kk);
        else
            k_select_cp_pool<<<gsel, 256, 0, stream>>>(score, y, T64, pmax, psum,
                                                       n, npad, NCH3);

        // ---- fused graph compaction for next layer (ELL, no scans) ----
        if (L == 0)
            k_compact<false><<<(M + TB - 1) / TB, TB, 0, stream>>>(remap, rowptrA, colA,
                                                                   (const int*)nullptr,
                                                                   colEA, degEA, dinv, M);
        else if (L == 1)
            k_compact<true><<<(M + TB - 1) / TB, TB, 0, stream>>>(remap, (const int*)nullptr,
                                                                  colEA, degEA,
                                                                  colEB, degEB, dinv, M);
        else if (L == 2)
            k_compact<true><<<(M + TB - 1) / TB, TB, 0, stream>>>(remap, (const int*)nullptr,
                                                                  colEB, degEB,
                                                                  colEA, degEA, dinv, M);

        M = NB * kk;
        xin = xout;
    }

    k_final2<<<NB, 128, 0, stream>>>(pmax, psum, metadata, convm_w, convm_b,
                                     fc_w, fc_b, fc2_w, fc2_b, (float*)d_out,
                                     Kk[3], NCH3);
}

// Round 13
// 361.753 us; speedup vs baseline: 1.0135x; 1.0135x over previous
//
#include <hip/hip_runtime.h>
#include <float.h>
#include <math.h>

#define NB 4            // graphs per batch
#define N0 40962        // nodes per graph at input
#define E0 983088       // total directed edges at layer 0
#define TK_CAP 4096     // candidate capacity for fine top-k select (32 KB LDS)
#define HBITS 12        // coarse histogram bits (4096 bins, LDS-resident)
#define EB 256          // edge-chunk blocks for bucketed CSR build
#define BSHIFT 10       // 1024 dst nodes per bucket
#define BKNODES (1 << BSHIFT)
#define NBKT 161        // ceil(163848 / 1024)
#define NSCAN (NBKT * EB)   // 41216
#define NB0 ((NSCAN + 1023) / 1024)   // 41 scan blocks for bcnt
#define CAP 32          // ELL row capacity for compacted layers (max in-deg ~24)

// ---------------- helpers ----------------

static __device__ __forceinline__ unsigned key32_of(float s) {
    unsigned u = __float_as_uint(s);
    return (u & 0x80000000u) ? ~u : (u | 0x80000000u);
}

static __device__ __forceinline__ unsigned long long key64_of(float s, int li) {
    unsigned u = key32_of(s);
    unsigned low = ~(unsigned)li;   // ties broken by smaller local index
    return ((unsigned long long)u << 32) | (unsigned long long)low;
}

static __device__ __forceinline__ float4 fma4(float s, float4 w, float4 a) {
    a.x = fmaf(s, w.x, a.x); a.y = fmaf(s, w.y, a.y);
    a.z = fmaf(s, w.z, a.z); a.w = fmaf(s, w.w, a.w);
    return a;
}

// exclusive prefix of bsum[0..nb0) into LDS bsumP (first wave; nb0 <= 64)
static __device__ __forceinline__ void bsum_prefix64(const int* __restrict__ bsum,
                                                     int nb0, int* bsumP) {
    if (threadIdx.x < 64) {
        int v = ((int)threadIdx.x < nb0) ? bsum[threadIdx.x] : 0;
        int pp = v;
#pragma unroll
        for (int off = 1; off < 64; off <<= 1) {
            int u = __shfl_up(pp, off, 64);
            if ((int)threadIdx.x >= off) pp += u;
        }
        bsumP[threadIdx.x] = pp - v;   // exclusive
    }
}

// ---------------- L0 bucketed CSR build (4 dispatches) ----------------

// A: per-(bucket, block) edge counts via LDS histogram
__global__ void k_bucket_count(const int* __restrict__ ei, int* __restrict__ bcnt) {
    __shared__ unsigned int h[NBKT];
    for (int i = threadIdx.x; i < NBKT; i += 256) h[i] = 0u;
    __syncthreads();
    const int chunk = (E0 + EB - 1) / EB;
    int i0 = blockIdx.x * chunk;
    int i1 = min(E0, i0 + chunk);
    for (int i = i0 + threadIdx.x; i < i1; i += 256)
        atomicAdd(&h[ei[E0 + i] >> BSHIFT], 1u);
    __syncthreads();
    for (int b = threadIdx.x; b < NBKT; b += 256)
        bcnt[b * EB + blockIdx.x] = (int)h[b];
}

// exclusive scan of bcnt (stage 1): 1024 elements per block, shuffle-based
__global__ void k_scan1(const int* __restrict__ in, int* __restrict__ out,
                        int* __restrict__ bsum, int M) {
    int t = threadIdx.x;
    int lane = t & 63, wv = t >> 6;
    int base = blockIdx.x * 1024 + t * 4;
    int d0 = (base + 0 < M) ? in[base + 0] : 0;
    int d1 = (base + 1 < M) ? in[base + 1] : 0;
    int d2 = (base + 2 < M) ? in[base + 2] : 0;
    int d3 = (base + 3 < M) ? in[base + 3] : 0;
    int tsum = d0 + d1 + d2 + d3;
    int p = tsum;
#pragma unroll
    for (int off = 1; off < 64; off <<= 1) {
        int u = __shfl_up(p, off, 64);
        if (lane >= off) p += u;
    }
    __shared__ int wsum[4];
    if (lane == 63) wsum[wv] = p;
    __syncthreads();
    int wadd = 0;
    for (int w = 0; w < wv; ++w) wadd += wsum[w];
    int texcl = p + wadd - tsum;
    if (base + 0 < M) out[base + 0] = texcl;
    if (base + 1 < M) out[base + 1] = texcl + d0;
    if (base + 2 < M) out[base + 2] = texcl + d0 + d1;
    if (base + 3 < M) out[base + 3] = texcl + d0 + d1 + d2;
    if (t == 255) bsum[blockIdx.x] = p + wadd;   // block total
}

// B: scatter (src,dst) pairs into bucketed buffer via LDS cursors (bsum prefix folded in)
__global__ void k_bucket_scatter(const int* __restrict__ ei, const int* __restrict__ boff,
                                 const int* __restrict__ bsum, int2* __restrict__ ebuf) {
    __shared__ int cur[NBKT];
    __shared__ int bsumP[64];
    bsum_prefix64(bsum, NB0, bsumP);
    __syncthreads();
    for (int i = threadIdx.x; i < NBKT; i += 256) {
        int idx = i * EB + blockIdx.x;
        cur[i] = boff[idx] + bsumP[idx >> 10];
    }
    __syncthreads();
    const int chunk = (E0 + EB - 1) / EB;
    int i0 = blockIdx.x * chunk;
    int i1 = min(E0, i0 + chunk);
    for (int i = i0 + threadIdx.x; i < i1; i += 256) {
        int s = ei[i], d = ei[E0 + i];
        int pos = atomicAdd(&cur[d >> BSHIFT], 1);
        ebuf[pos] = make_int2(s, d);
    }
}

// C (fused deg + scan + place): per bucket, count in-degrees into LDS, write dinv,
// LDS-scan degrees to per-node cursors (rowptr[base+i] = e0 + excl_scan — bitwise
// identical to the old global scan since edges are bucketed contiguously), then
// place edges into CSR. Replaces k_bucket_deg + k_scan1(degi) + k_scan23 +
// k_bucket_place (4 dispatches -> 1).
__global__ void __launch_bounds__(1024) k_bucket_degplace(
        const int2* __restrict__ ebuf, const int* __restrict__ boff,
        const int* __restrict__ bsum, float* __restrict__ dinv,
        int* __restrict__ rowptr, int* __restrict__ col, int M) {
    __shared__ unsigned int h[BKNODES];
    __shared__ int bsumP[64];
    __shared__ int wsc[16];
    bsum_prefix64(bsum, NB0, bsumP);
    int b = blockIdx.x;
    int base = b << BSHIFT;
    int range = min(BKNODES, M - base);
    int t = threadIdx.x;
    for (int i = t; i < range; i += 1024) h[i] = 0u;
    __syncthreads();
    int i0x = b * EB;
    int e0 = boff[i0x] + bsumP[i0x >> 10];
    int e1 = E0;
    if (b + 1 < NBKT) {
        int i1x = (b + 1) * EB;
        e1 = boff[i1x] + bsumP[i1x >> 10];
    }
    // phase 1: in-degree histogram
    for (int i = e0 + t; i < e1; i += 1024)
        atomicAdd(&h[ebuf[i].y - base], 1u);
    __syncthreads();
    // phase 2: dinv + intra-bucket exclusive scan (1024 threads, one elem each)
    int v = (t < range) ? (int)h[t] : 0;
    if (t < range) dinv[base + t] = rsqrtf((float)v + 1.0f);
    int lane = t & 63, wv = t >> 6;
    int p = v;
#pragma unroll
    for (int off = 1; off < 64; off <<= 1) {
        int u = __shfl_up(p, off, 64);
        if (lane >= off) p += u;
    }
    if (lane == 63) wsc[wv] = p;
    __syncthreads();
    int wadd = 0;
    for (int w = 0; w < wv; ++w) wadd += wsc[w];
    int excl = p + wadd - v;           // exclusive prefix within bucket
    int cur0 = e0 + excl;
    if (t < range) rowptr[base + t] = cur0;
    if (b == NBKT - 1 && t == range - 1) rowptr[M] = E0;
    __syncthreads();                   // all reads of h done before overwrite
    if (t < range) h[t] = (unsigned)cur0;   // h becomes the placement cursor
    __syncthreads();
    // phase 3: place edges
    for (int i = e0 + t; i < e1; i += 1024) {
        int2 sd = ebuf[i];
        int pos = (int)atomicAdd(&h[sd.y - base], 1u);
        col[pos] = sd.x;
    }
}

// ---------------- fused graph compaction (ELL output) ----------------

template <bool ELLIN>
__global__ void k_compact(const int* __restrict__ remap, const int* __restrict__ rpO,
                          const int* __restrict__ colO, const int* __restrict__ degO,
                          int* __restrict__ colN, int* __restrict__ degN,
                          float* __restrict__ dinvN, int Mold) {
    int m = blockIdx.x * blockDim.x + threadIdx.x;
    if (m >= Mold) return;
    int nd = remap[m];
    if (nd < 0) return;
    int j0, j1;
    if (ELLIN) { j0 = m * CAP; j1 = j0 + degO[m]; }
    else       { j0 = rpO[m];  j1 = rpO[m + 1]; }
    int w = nd * CAP;
    int c = 0;
    for (int j = j0; j < j1; ++j) {
        int rs = remap[colO[j]];
        if (rs >= 0) { colN[w + c] = rs; ++c; }
    }
    degN[nd] = c;
    dinvN[nd] = rsqrtf((float)c + 1.0f);
}

// ---------------- fused gather + dense layer ----------------
// Phase 1: aggregate the block's RPB rows into an LDS tile (CSR at L0, ELL after).
// Phase 2: mm + bias + relu + score from LDS. L0CSR: spill tile to axg (source for
// the select-recompute path). WY: write y (L1..L3 copy path).
template <int FI, int FO, bool WY, bool L0CSR>
__global__ void __launch_bounds__(256) k_gmm(
        const float* __restrict__ x,
        const int* __restrict__ rowptr, const int* __restrict__ colC,
        const int* __restrict__ colE, const int* __restrict__ deg,
        const float* __restrict__ dinv,
        const float* __restrict__ W, const float* __restrict__ bias,
        const float* __restrict__ pvec,
        float* __restrict__ y, float* __restrict__ score, float* __restrict__ axg,
        int M, int n, int npad) {
    constexpr int Q = FO / 4;            // lanes per row-quad
    constexpr int RPB = (256 / Q) * 4;   // rows per block (128/64/32/32)
    constexpr int STR = FI + 4;          // padded LDS row stride (16B-aligned)
    constexpr int ELEMS = RPB * FI;
    __shared__ float axs[RPB * STR];
    int row0 = blockIdx.x * RPB;

    // ---- phase 1: aggregation into LDS ----
    for (int idx = threadIdx.x; idx < ELEMS; idx += 256) {
        int rl = idx / FI, f = idx - rl * FI;
        int row = row0 + rl;
        if (row < M) {
            float dd = dinv[row];
            float invdeg = dd * dd;
            float acc = x[(size_t)row * FI + f] * invdeg;
            if (L0CSR) {
                int j0 = rowptr[row], j1 = rowptr[row + 1];
                for (int j = j0; j < j1; ++j) {
                    int s = colC[j];
                    float nrm = dd * dinv[s];
                    acc = fmaf(x[(size_t)s * FI + f], nrm, acc);
                }
            } else {
                int dg = min(deg[row], CAP);
                const int* cr = colE + (size_t)row * CAP;
                for (int j = 0; j < dg; ++j) {
                    int s = cr[j];
                    float nrm = dd * dinv[s];
                    acc = fmaf(x[(size_t)s * FI + f], nrm, acc);
                }
            }
            axs[rl * STR + f] = acc;
        }
    }
    __syncthreads();
    if (L0CSR) {   // spill tile to global ax for the select-recompute path
        for (int idx = threadIdx.x; idx < ELEMS; idx += 256) {
            int rl = idx / FI, f = idx - rl * FI;
            int row = row0 + rl;
            if (row < M) axg[(size_t)row * FI + f] = axs[rl * STR + f];
        }
    }

    // ---- phase 2: mm body, row-quad from LDS ----
    int q = threadIdx.x % Q;
    int lrow = (threadIdx.x / Q) * 4;
    int row = row0 + lrow;
    if (row >= M) return;   // M divisible by 4 -> quads never straddle M
    const float4* x0 = (const float4*)(axs + (lrow + 0) * STR);
    const float4* x1 = (const float4*)(axs + (lrow + 1) * STR);
    const float4* x2 = (const float4*)(axs + (lrow + 2) * STR);
    const float4* x3 = (const float4*)(axs + (lrow + 3) * STR);
    const float4* W4 = (const float4*)W;
    float4 a0 = {0.f, 0.f, 0.f, 0.f}, a1 = {0.f, 0.f, 0.f, 0.f};
    float4 a2 = {0.f, 0.f, 0.f, 0.f}, a3 = {0.f, 0.f, 0.f, 0.f};
#pragma unroll 2
    for (int c = 0; c < FI / 4; ++c) {
        float4 v0 = x0[c], v1 = x1[c], v2 = x2[c], v3 = x3[c];
        const float4* wr = W4 + (size_t)(c * 4) * Q + q;
        float4 w;
        w = wr[0 * Q];
        a0 = fma4(v0.x, w, a0); a1 = fma4(v1.x, w, a1);
        a2 = fma4(v2.x, w, a2); a3 = fma4(v3.x, w, a3);
        w = wr[1 * Q];
        a0 = fma4(v0.y, w, a0); a1 = fma4(v1.y, w, a1);
        a2 = fma4(v2.y, w, a2); a3 = fma4(v3.y, w, a3);
        w = wr[2 * Q];
        a0 = fma4(v0.z, w, a0); a1 = fma4(v1.z, w, a1);
        a2 = fma4(v2.z, w, a2); a3 = fma4(v3.z, w, a3);
        w = wr[3 * Q];
        a0 = fma4(v0.w, w, a0); a1 = fma4(v1.w, w, a1);
        a2 = fma4(v2.w, w, a2); a3 = fma4(v3.w, w, a3);
    }
    float4 b4 = ((const float4*)bias)[q];
    float4 o0, o1, o2, o3;
    o0.x = fmaxf(a0.x + b4.x, 0.f); o0.y = fmaxf(a0.y + b4.y, 0.f);
    o0.z = fmaxf(a0.z + b4.z, 0.f); o0.w = fmaxf(a0.w + b4.w, 0.f);
    o1.x = fmaxf(a1.x + b4.x, 0.f); o1.y = fmaxf(a1.y + b4.y, 0.f);
    o1.z = fmaxf(a1.z + b4.z, 0.f); o1.w = fmaxf(a1.w + b4.w, 0.f);
    o2.x = fmaxf(a2.x + b4.x, 0.f); o2.y = fmaxf(a2.y + b4.y, 0.f);
    o2.z = fmaxf(a2.z + b4.z, 0.f); o2.w = fmaxf(a2.w + b4.w, 0.f);
    o3.x = fmaxf(a3.x + b4.x, 0.f); o3.y = fmaxf(a3.y + b4.y, 0.f);
    o3.z = fmaxf(a3.z + b4.z, 0.f); o3.w = fmaxf(a3.w + b4.w, 0.f);
    if (WY) {
        ((float4*)(y + (size_t)(row + 0) * FO))[q] = o0;
        ((float4*)(y + (size_t)(row + 1) * FO))[q] = o1;
        ((float4*)(y + (size_t)(row + 2) * FO))[q] = o2;
        ((float4*)(y + (size_t)(row + 3) * FO))[q] = o3;
    }
    float4 p4 = ((const float4*)pvec)[q];
    float d0 = o0.x * p4.x + o0.y * p4.y + o0.z * p4.z + o0.w * p4.w;
    float d1 = o1.x * p4.x + o1.y * p4.y + o1.z * p4.z + o1.w * p4.w;
    float d2 = o2.x * p4.x + o2.y * p4.y + o2.z * p4.z + o2.w * p4.w;
    float d3 = o3.x * p4.x + o3.y * p4.y + o3.z * p4.z + o3.w * p4.w;
    float pn = p4.x * p4.x + p4.y * p4.y + p4.z * p4.z + p4.w * p4.w;
#pragma unroll
    for (int off = Q / 2; off > 0; off >>= 1) {
        d0 += __shfl_xor(d0, off, 64);
        d1 += __shfl_xor(d1, off, 64);
        d2 += __shfl_xor(d2, off, 64);
        d3 += __shfl_xor(d3, off, 64);
        pn += __shfl_xor(pn, off, 64);
    }
    if (q == 0) {
        float inv = rsqrtf(pn);
        float s[4] = {d0 * inv, d1 * inv, d2 * inv, d3 * inv};
#pragma unroll
        for (int j = 0; j < 4; ++j) {
            int rj = row + j;
            int b = rj / n;
            int i = rj - b * n;
            score[(size_t)b * npad + i] = s[j];
        }
    }
}

// ---------------- top-k (coarse hist fused in; R6 fine-radix structure) ----------

__global__ void __launch_bounds__(1024) k_topk_fine(
        const float* __restrict__ score,
        unsigned long long* __restrict__ T64, int* __restrict__ cnt,
        int n, int npad, int k) {
    int b = blockIdx.x;
    int t = threadIdx.x;
    int lane = t & 63;
    int wv = t >> 6;                 // 16 waves
    const float* sc = score + (size_t)b * npad;
    __shared__ unsigned int hist12s[1 << HBITS];   // 16 KB, block-local coarse hist
    __shared__ unsigned long long cand[TK_CAP];    // 32 KB
    __shared__ unsigned int hist[256];
    __shared__ int wsum16[16];
    __shared__ int s_P12, s_r, s_c, s_rr, s_done, s_cc, s_m;
    __shared__ unsigned s_low;
    __shared__ unsigned long long s_prefix;

    // ---- build 4096-bin coarse histogram in LDS ----
    for (int i = t; i < (1 << HBITS); i += 1024) hist12s[i] = 0u;
    __syncthreads();
    for (int i = t << 2; i < n; i += 4096) {
        float4 v = *(const float4*)(sc + i);   // 16B-aligned (npad%4==0)
        atomicAdd(&hist12s[key32_of(v.x) >> (32 - HBITS)], 1u);
        if (i + 1 < n) atomicAdd(&hist12s[key32_of(v.y) >> (32 - HBITS)], 1u);
        if (i + 2 < n) atomicAdd(&hist12s[key32_of(v.z) >> (32 - HBITS)], 1u);
        if (i + 3 < n) atomicAdd(&hist12s[key32_of(v.w) >> (32 - HBITS)], 1u);
    }
    __syncthreads();

    // ---- coarse phase: suffix scan of 4096 bins (4 bins/thread) ----
    uint4 g4 = ((const uint4*)hist12s)[t];
    int sum = (int)(g4.x + g4.y + g4.z + g4.w);
    int ssum = sum;
#pragma unroll
    for (int off = 1; off < 64; off <<= 1) {
        int v = __shfl_down(ssum, off, 64);
        if (lane + off < 64) ssum += v;
    }
    if (lane == 0) wsum16[wv] = ssum;
    __syncthreads();
    {
        int hi = 0;
        for (int w = wv + 1; w < 16; ++w) hi += wsum16[w];
        int suffIncl = ssum + hi;
        int cumAbove = suffIncl - sum;
        if (cumAbove < k && suffIncl >= k) {      // unique thread owns threshold chunk
            unsigned bv0 = g4.x, bv1 = g4.y, bv2 = g4.z, bv3 = g4.w;
            int base = t << 2;
            int cum = cumAbove;
            int cb;
            cb = (int)bv3; cum += cb;
            if (cum >= k) { s_P12 = base + 3; s_r = k - (cum - cb); s_c = cb; }
            else {
                cb = (int)bv2; cum += cb;
                if (cum >= k) { s_P12 = base + 2; s_r = k - (cum - cb); s_c = cb; }
                else {
                    cb = (int)bv1; cum += cb;
                    if (cum >= k) { s_P12 = base + 1; s_r = k - (cum - cb); s_c = cb; }
                    else {
                        cb = (int)bv0; cum += cb;
                        s_P12 = base; s_r = k - (cum - cb); s_c = cb;
                    }
                }
            }
        }
    }
    if (t == 0) s_cc = 0;
    __syncthreads();
    int P12 = s_P12, r = s_r, c = s_c;

    // ---- candidate collection: float4 over padded score; matches are rare ----
    if (c <= TK_CAP) {
        for (int i = t << 2; i < n; i += 4096) {
            float4 v = *(const float4*)(sc + i);
            unsigned u0 = key32_of(v.x), u1 = key32_of(v.y);
            unsigned u2 = key32_of(v.z), u3 = key32_of(v.w);
            if ((int)(u0 >> (32 - HBITS)) == P12) {
                int pos = atomicAdd(&s_cc, 1);
                cand[pos] = ((unsigned long long)u0 << 32) | (unsigned long long)(~(unsigned)(i + 0));
            }
            if (i + 1 < n && (int)(u1 >> (32 - HBITS)) == P12) {
                int pos = atomicAdd(&s_cc, 1);
                cand[pos] = ((unsigned long long)u1 << 32) | (unsigned long long)(~(unsigned)(i + 1));
            }
            if (i + 2 < n && (int)(u2 >> (32 - HBITS)) == P12) {
                int pos = atomicAdd(&s_cc, 1);
                cand[pos] = ((unsigned long long)u2 << 32) | (unsigned long long)(~(unsigned)(i + 2));
            }
            if (i + 3 < n && (int)(u3 >> (32 - HBITS)) == P12) {
                int pos = atomicAdd(&s_cc, 1);
                cand[pos] = ((unsigned long long)u3 << 32) | (unsigned long long)(~(unsigned)(i + 3));
            }
        }
    }
    if (t == 0) {
        s_prefix = ((unsigned long long)(unsigned)P12) << (64 - HBITS);
        s_rr = r;
        s_done = 0;
        s_m = 0;
        s_low = 0u;
    }
    if (t < 256) hist[t] = 0u;
    __syncthreads();

    if (c <= TK_CAP) {
        // ---- in-LDS fine radix over candidates; 2 barriers/pass ----
        int cc = s_cc;
        const int shf[7] = {44, 36, 32, 24, 16, 8, 0};
        const int wid[7] = {8, 8, 4, 8, 8, 8, 8};
        for (int pi = 0; pi < 7; ++pi) {
            if (s_done) break;
            if (pi == 3 && s_m == 1) {
                unsigned long long pref = s_prefix;
                for (int i = t; i < cc; i += 1024) {
                    unsigned long long key = cand[i];
                    if ((key >> 32) == (pref >> 32)) s_low = (unsigned)key;
                }
                __syncthreads();
                if (t == 0) { s_prefix = pref | (unsigned long long)s_low; s_done = 1; }
                __syncthreads();
                break;
            }
            int shift = shf[pi], wd = wid[pi];
            int nbins = 1 << wd;
            unsigned mask = (unsigned)nbins - 1u;
            unsigned long long prefix = s_prefix;
            int hs = shift + wd;
            for (int i = t; i < cc; i += 1024) {
                unsigned long long key = cand[i];
                if ((key >> hs) == (prefix >> hs))
                    atomicAdd(&hist[(unsigned)(key >> shift) & mask], 1u);
            }
            __syncthreads();
            if (t < 64) {
                int bpl = (nbins + 63) >> 6;
                int b0 = t * bpl;
                int cl[4];
                int lsum = 0;
#pragma unroll
                for (int j = 0; j < 4; ++j) {
                    int bi = b0 + j;
                    int v = (j < bpl && bi < nbins) ? (int)hist[bi] : 0;
                    cl[j] = v;
                    lsum += v;
                }
                int suf = lsum;
#pragma unroll
                for (int off = 1; off < 64; off <<= 1) {
                    int v = __shfl_down(suf, off, 64);
                    if (t + off < 64) suf += v;
                }
                int rr = s_rr;
                int run = suf - lsum;
                for (int j = bpl - 1; j >= 0; --j) {
                    int cb = cl[j];
                    int suffIncl = run + cb;
                    if (run < rr && rr <= suffIncl) {
                        s_prefix = prefix | ((unsigned long long)(b0 + j) << shift);
                        s_rr = rr - run;
                        s_m = cb;
                        if (rr == suffIncl) s_done = 1;
                    }
                    run = suffIncl;
                }
#pragma unroll
                for (int j = 0; j < 4; ++j)
                    if (j < bpl && b0 + j < nbins) hist[b0 + j] = 0u;
            }
            __syncthreads();
        }
    } else {
        // ---- fallback: full-rescan multi-wave path ----
        const int shifts[7] = {44, 36, 28, 20, 12, 4, 0};
        const int widths[7] = {8, 8, 8, 8, 8, 8, 4};
        for (int pi = 0; pi < 7; ++pi) {
            if (s_done) break;
            int shift = shifts[pi], wd = widths[pi];
            int nbins = 1 << wd;
            unsigned mask = (unsigned)nbins - 1u;
            if (t < 256) hist[t] = 0u;
            __syncthreads();
            unsigned long long prefix = s_prefix;
            int rr = s_rr;
            int hs = shift + wd;
            for (int i = t; i < n; i += 1024) {
                unsigned long long key = key64_of(sc[i], i);
                if ((key >> hs) == (prefix >> hs))
                    atomicAdd(&hist[(unsigned)(key >> shift) & mask], 1u);
            }
            __syncthreads();
            int cb = 0, suff = 0;
            if (t < 256) {
                cb = (t < nbins) ? (int)hist[t] : 0;
                suff = cb;
#pragma unroll
                for (int off = 1; off < 64; off <<= 1) {
                    int v = __shfl_down(suff, off, 64);
                    if (lane + off < 64) suff += v;
                }
                if (lane == 0) wsum16[wv] = suff;
            }
            __syncthreads();
            if (t < nbins) {
                int nw = (nbins + 63) >> 6;
                int hi = 0;
                for (int w = wv + 1; w < nw; ++w) hi += wsum16[w];
                int suffIncl = suff + hi;
                int suffExcl = suffIncl - cb;
                if (suffExcl < rr && rr <= suffIncl) {
                    s_prefix = prefix | ((unsigned long long)t << shift);
                    s_rr = rr - suffExcl;
                    if (rr == suffIncl) s_done = 1;
                }
            }
            __syncthreads();
        }
    }
    if (t == 0) { T64[b] = s_prefix; cnt[b] = 0; }
}

// ---------------- select (L0: recompute y for kept rows from ax) ----------------
template <int FI, int FO>
__global__ void k_select_rc(const float* __restrict__ score, const float* __restrict__ ax,
                            const float* __restrict__ W, const float* __restrict__ bias,
                            const unsigned long long* __restrict__ T64, int* __restrict__ cnt,
                            int* __restrict__ remap, float* __restrict__ xout,
                            int n, int npad, int k) {
    constexpr int Q = FO / 4;
    constexpr int RPI = 256 / Q;
    int b = blockIdx.y;
    int i = blockIdx.x * 256 + threadIdx.x;
    bool keep = false;
    float s = 0.f;
    if (i < n) {
        s = score[(size_t)b * npad + i];
        keep = key64_of(s, i) >= T64[b];
    }
    unsigned long long mask = __ballot(keep);
    int lane = threadIdx.x & 63;
    int wv = threadIdx.x >> 6;
    int lp = __popcll(mask & ((1ULL << lane) - 1ULL));
    __shared__ int woff[4];
    __shared__ int blockBase, nkept;
    __shared__ int km[256];
    __shared__ float ks[256];
    if (lane == 0) woff[wv] = __popcll(mask);
    __syncthreads();
    if (threadIdx.x == 0) {
        int t0 = woff[0], t1 = woff[1], t2 = woff[2], t3 = woff[3];
        woff[0] = 0; woff[1] = t0; woff[2] = t0 + t1; woff[3] = t0 + t1 + t2;
        int tot = t0 + t1 + t2 + t3;
        nkept = tot;
        blockBase = atomicAdd(&cnt[b], tot);
    }
    __syncthreads();
    int bb = blockBase;
    if (i < n) {
        if (keep) {
            int idx = woff[wv] + lp;
            km[idx] = i;
            ks[idx] = tanhf(s);
            remap[b * n + i] = b * k + bb + idx;
        } else {
            remap[b * n + i] = -1;
        }
    }
    __syncthreads();
    int q = threadIdx.x % Q;
    int rslot = threadIdx.x / Q;
    const float4* W4 = (const float4*)W;
    float4 b4 = ((const float4*)bias)[q];
    float4* x4 = (float4*)xout + ((size_t)b * k + bb) * Q;
    int nk = nkept;
    for (int r0 = rslot; r0 < nk; r0 += RPI) {
        int gi = km[r0];
        const float4* xr = (const float4*)(ax + ((size_t)b * n + gi) * FI);
        float4 a0 = {0.f, 0.f, 0.f, 0.f};
#pragma unroll 2
        for (int c = 0; c < FI / 4; ++c) {
            float4 v0 = xr[c];
            const float4* wr = W4 + (size_t)(c * 4) * Q + q;
            a0 = fma4(v0.x, wr[0 * Q], a0);
            a0 = fma4(v0.y, wr[1 * Q], a0);
            a0 = fma4(v0.z, wr[2 * Q], a0);
            a0 = fma4(v0.w, wr[3 * Q], a0);
        }
        float4 o;
        o.x = fmaxf(a0.x + b4.x, 0.f);
        o.y = fmaxf(a0.y + b4.y, 0.f);
        o.z = fmaxf(a0.z + b4.z, 0.f);
        o.w = fmaxf(a0.w + b4.w, 0.f);
        float sc_ = ks[r0];
        float4 ov;
        ov.x = o.x * sc_; ov.y = o.y * sc_; ov.z = o.z * sc_; ov.w = o.w * sc_;
        x4[(size_t)r0 * Q + q] = ov;
    }
}

// select copy-path (L1..L2): coalesced float4 row copy of kept rows from y
template <int FO>
__global__ void k_select_cp(const float* __restrict__ score, const float* __restrict__ y,
                            const unsigned long long* __restrict__ T64, int* __restrict__ cnt,
                            int* __restrict__ remap, float* __restrict__ xout,
                            int n, int npad, int k) {
    constexpr int Fo4 = FO / 4;
    int b = blockIdx.y;
    int i = blockIdx.x * 256 + threadIdx.x;
    bool keep = false;
    float s = 0.f;
    if (i < n) {
        s = score[(size_t)b * npad + i];
        keep = key64_of(s, i) >= T64[b];
    }
    unsigned long long mask = __ballot(keep);
    int lane = threadIdx.x & 63;
    int wv = threadIdx.x >> 6;
    int lp = __popcll(mask & ((1ULL << lane) - 1ULL));
    __shared__ int woff[4];
    __shared__ int blockBase, nkept;
    __shared__ int km[256];
    __shared__ float ks[256];
    if (lane == 0) woff[wv] = __popcll(mask);
    __syncthreads();
    if (threadIdx.x == 0) {
        int t0 = woff[0], t1 = woff[1], t2 = woff[2], t3 = woff[3];
        woff[0] = 0; woff[1] = t0; woff[2] = t0 + t1; woff[3] = t0 + t1 + t2;
        int tot = t0 + t1 + t2 + t3;
        nkept = tot;
        blockBase = atomicAdd(&cnt[b], tot);
    }
    __syncthreads();
    int bb = blockBase;
    if (i < n) {
        if (keep) {
            int idx = woff[wv] + lp;
            km[idx] = i;
            ks[idx] = tanhf(s);
            remap[b * n + i] = b * k + bb + idx;
        } else {
            remap[b * n + i] = -1;
        }
    }
    __syncthreads();
    int tot4 = nkept * Fo4;
    const float4* y4 = (const float4*)y + (size_t)b * n * Fo4;
    float4* x4 = (float4*)xout + ((size_t)b * k + bb) * Fo4;
    for (int j = threadIdx.x; j < tot4; j += 256) {
        int r = j / Fo4;
        int cc = j & (Fo4 - 1);
        float4 v = y4[(size_t)km[r] * Fo4 + cc];
        float sc_ = ks[r];
        float4 o;
        o.x = v.x * sc_; o.y = v.y * sc_; o.z = v.z * sc_; o.w = v.w * sc_;
        x4[(size_t)r * Fo4 + cc] = o;
    }
}

// L3 select + pooling fused: pool (max/sum) the block's kept scaled rows directly
// into per-block partials. No xout / remap at L3 (nothing consumes them).
__global__ void k_select_cp_pool(const float* __restrict__ score, const float* __restrict__ y,
                                 const unsigned long long* __restrict__ T64,
                                 float* __restrict__ pmax, float* __restrict__ psum,
                                 int n, int npad, int nch) {
    int b = blockIdx.y;
    int i = blockIdx.x * 256 + threadIdx.x;
    bool keep = false;
    float s = 0.f;
    if (i < n) {
        s = score[(size_t)b * npad + i];
        keep = key64_of(s, i) >= T64[b];
    }
    unsigned long long mask = __ballot(keep);
    int lane = threadIdx.x & 63;
    int wv = threadIdx.x >> 6;
    int lp = __popcll(mask & ((1ULL << lane) - 1ULL));
    __shared__ int woff[4];
    __shared__ int nkept;
    __shared__ int km[256];
    __shared__ float ks[256];
    __shared__ float4 redm[256];
    __shared__ float4 reds[256];
    if (lane == 0) woff[wv] = __popcll(mask);
    __syncthreads();
    if (threadIdx.x == 0) {
        int t0 = woff[0], t1 = woff[1], t2 = woff[2], t3 = woff[3];
        woff[0] = 0; woff[1] = t0; woff[2] = t0 + t1; woff[3] = t0 + t1 + t2;
        nkept = t0 + t1 + t2 + t3;
    }
    __syncthreads();
    if (i < n && keep) {
        int idx = woff[wv] + lp;
        km[idx] = i;
        ks[idx] = tanhf(s);
    }
    __syncthreads();
    // pooled accumulation: thread covers fixed float4 column cc = tid&31 (256%32==0)
    int cc = threadIdx.x & 31;
    float4 mx = {-FLT_MAX, -FLT_MAX, -FLT_MAX, -FLT_MAX};
    float4 sm = {0.f, 0.f, 0.f, 0.f};
    int tot4 = nkept * 32;
    const float4* y4 = (const float4*)y + (size_t)b * n * 32;
    for (int j = threadIdx.x; j < tot4; j += 256) {
        int r = j >> 5;
        float4 v = y4[(size_t)km[r] * 32 + cc];
        float sc_ = ks[r];
        v.x *= sc_; v.y *= sc_; v.z *= sc_; v.w *= sc_;
        mx.x = fmaxf(mx.x, v.x); mx.y = fmaxf(mx.y, v.y);
        mx.z = fmaxf(mx.z, v.z); mx.w = fmaxf(mx.w, v.w);
        sm.x += v.x; sm.y += v.y; sm.z += v.z; sm.w += v.w;
    }
    redm[threadIdx.x] = mx;
    reds[threadIdx.x] = sm;
    __syncthreads();
    if (threadIdx.x < 32) {
        float4 m = redm[threadIdx.x];
        float4 ss = reds[threadIdx.x];
        for (int g = 1; g < 8; ++g) {
            float4 m2 = redm[threadIdx.x + 32 * g];
            float4 s2 = reds[threadIdx.x + 32 * g];
            m.x = fmaxf(m.x, m2.x); m.y = fmaxf(m.y, m2.y);
            m.z = fmaxf(m.z, m2.z); m.w = fmaxf(m.w, m2.w);
            ss.x += s2.x; ss.y += s2.y; ss.z += s2.z; ss.w += s2.w;
        }
        size_t o = ((size_t)b * nch + blockIdx.x) * 32 + threadIdx.x;
        ((float4*)pmax)[o] = m;
        ((float4*)psum)[o] = ss;
    }
}

// final: one block (128 threads) per graph: combine partials + metadata conv + fc + fc2
__global__ void k_final2(const float* __restrict__ pmax, const float* __restrict__ psum,
                         const float* __restrict__ metadata,
                         const float* __restrict__ convm_w, const float* __restrict__ convm_b,
                         const float* __restrict__ fc_w, const float* __restrict__ fc_b,
                         const float* __restrict__ fc2_w, const float* __restrict__ fc2_b,
                         float* __restrict__ out, int K3, int nch) {
    int b = blockIdx.x;
    int f = threadIdx.x;   // 0..127
    __shared__ float xc[260];
    __shared__ float red[128];
    float mx = -FLT_MAX, sm = 0.f;
    for (int c = 0; c < nch; ++c) {
        int o = (b * nch + c) * 128 + f;
        mx = fmaxf(mx, pmax[o]);
        sm += psum[o];
    }
    xc[f] = mx;
    xc[128 + f] = sm / (float)K3;
    if (f < 4) {
        float mv = metadata[b] * convm_w[f] + convm_b[f];
        xc[256 + f] = mv > 0.f ? mv : 0.f;
    }
    __syncthreads();
    float acc = fc_b[f];
    for (int i = 0; i < 260; ++i) acc = fmaf(xc[i], fc_w[i * 128 + f], acc);
    acc = acc > 0.f ? acc : 0.f;
    red[f] = acc * fc2_w[f];
    __syncthreads();
    for (int s2 = 64; s2 > 0; s2 >>= 1) {
        if (f < s2) red[f] += red[f + s2];
        __syncthreads();
    }
    if (f == 0) out[b] = red[0] + fc2_b[0];
}

// ---------------- launch ----------------

extern "C" void kernel_launch(void* const* d_in, const int* in_sizes, int n_in,
                              void* d_out, int out_size, void* d_ws, size_t ws_size,
                              hipStream_t stream) {
    const float* x0       = (const float*)d_in[0];
    const int*   ei       = (const int*)d_in[1];
    const float* metadata = (const float*)d_in[2];
    const float* W[4]  = {(const float*)d_in[3], (const float*)d_in[6],
                          (const float*)d_in[9], (const float*)d_in[12]};
    const float* bs[4] = {(const float*)d_in[4], (const float*)d_in[7],
                          (const float*)d_in[10], (const float*)d_in[13]};
    const float* pv[4] = {(const float*)d_in[5], (const float*)d_in[8],
                          (const float*)d_in[11], (const float*)d_in[14]};
    const float* convm_w = (const float*)d_in[15];
    const float* convm_b = (const float*)d_in[16];
    const float* fc_w    = (const float*)d_in[17];
    const float* fc_b    = (const float*)d_in[18];
    const float* fc2_w   = (const float*)d_in[19];
    const float* fc2_b   = (const float*)d_in[20];

    // workspace bump allocation
    const size_t AXMAX = 655392;           // L0 ax spill: 163848*4
    const size_t YMAX  = 5243392;          // max M*FO (L1: 81924*64)
    const size_t XMAX  = 2621952;
    const size_t MMAX  = NB * (size_t)N0;  // 163848
    const int    NCH3  = (5121 + 255) / 256;   // 21 pooling partials per graph

    char* p = (char*)d_ws;
    size_t off = 0;
    auto alloc = [&](size_t bytes) -> char* {
        char* r = p + off;
        off = (off + bytes + 255) & ~(size_t)255;
        return r;
    };
    float* ax     = (float*)alloc(AXMAX * 4);         // L0 only (select_rc source)
    float* y      = (float*)alloc(YMAX * 4);          // L1..L3 copy path
    float* xb0    = (float*)alloc(XMAX * 4);
    float* xb1    = (float*)alloc(XMAX * 4);
    float* dinv   = (float*)alloc(MMAX * 4);
    float* score  = (float*)alloc((MMAX + 64) * 4);   // padded per-graph stride
    int*   remap  = (int*)alloc(MMAX * 4);
    int*   degEA  = (int*)alloc(81924 * 4);           // ELL degrees ping
    int*   degEB  = (int*)alloc(40964 * 4);           // ELL degrees pong
    int*   rowptrA= (int*)alloc((MMAX + 1) * 4);
    int*   colA   = (int*)alloc(E0 * 4);
    int*   colEA  = (int*)alloc((size_t)81924 * CAP * 4);   // 10.5 MB
    int*   colEB  = (int*)alloc((size_t)40964 * CAP * 4);   // 5.25 MB
    int2*  ebuf   = (int2*)alloc((size_t)E0 * 8);
    int*   bcnt   = (int*)alloc(NSCAN * 4);
    int*   boff   = (int*)alloc(NSCAN * 4);
    int*   bsumA  = (int*)alloc(260 * 4);
    float* pmax   = (float*)alloc((size_t)NB * NCH3 * 128 * 4);
    float* psum   = (float*)alloc((size_t)NB * NCH3 * 128 * 4);
    unsigned long long* T64 = (unsigned long long*)alloc(NB * 8);
    int*   cnt    = (int*)alloc(NB * 4);
    (void)ws_size; (void)n_in; (void)in_sizes; (void)out_size;

    const int Kk[4] = {20481, 10241, 5121, 2561};
    const int TB = 256;

    // ---- L0 CSR build: bucketed, 4 dispatches (deg+scan+place fused) ----
    int M = NB * N0;
    {
        k_bucket_count<<<EB, 256, 0, stream>>>(ei, bcnt);
        k_scan1<<<NB0, 256, 0, stream>>>(bcnt, boff, bsumA, NSCAN);
        k_bucket_scatter<<<EB, 256, 0, stream>>>(ei, boff, bsumA, ebuf);
        k_bucket_degplace<<<NBKT, 1024, 0, stream>>>(ebuf, boff, bsumA, dinv,
                                                     rowptrA, colA, M);
    }

    const float* xin = x0;
    float* xbufs[2] = {xb0, xb1};

    for (int L = 0; L < 4; ++L) {
        int n = M / NB, kk = Kk[L];
        int npad = (n + 3) & ~3;

        // ---- fused gather + matmul + bias + relu + score ----
        if (L == 0) {
            int nbk = (M + 127) / 128;   // RPB=128
            k_gmm<4, 32, false, true><<<nbk, 256, 0, stream>>>(
                xin, rowptrA, colA, nullptr, nullptr, dinv,
                W[L], bs[L], pv[L], y, score, ax, M, n, npad);
        } else if (L == 1) {
            int nbk = (M + 63) / 64;     // RPB=64
            k_gmm<32, 64, true, false><<<nbk, 256, 0, stream>>>(
                xin, nullptr, nullptr, colEA, degEA, dinv,
                W[L], bs[L], pv[L], y, score, nullptr, M, n, npad);
        } else if (L == 2) {
            int nbk = (M + 31) / 32;     // RPB=32
            k_gmm<64, 128, true, false><<<nbk, 256, 0, stream>>>(
                xin, nullptr, nullptr, colEB, degEB, dinv,
                W[L], bs[L], pv[L], y, score, nullptr, M, n, npad);
        } else {
            int nbk = (M + 31) / 32;     // RPB=32
            k_gmm<128, 128, true, false><<<nbk, 256, 0, stream>>>(
                xin, nullptr, nullptr, colEA, degEA, dinv,
                W[L], bs[L], pv[L], y, score, nullptr, M, n, npad);
        }

        // ---- top-k (coarse hist fused) ----
        k_topk_fine<<<NB, 1024, 0, stream>>>(score, T64, cnt, n, npad, kk);
        float* xout = xbufs[L & 1];
        dim3 gsel((n + 255) / 256, NB);
        if (L == 0)
            k_select_rc<4, 32><<<gsel, 256, 0, stream>>>(score, ax, W[L], bs[L], T64, cnt,
                                                         remap, xout, n, npad, kk);
        else if (L == 1)
            k_select_cp<64><<<gsel, 256, 0, stream>>>(score, y, T64, cnt,
                                                      remap, xout, n, npad, kk);
        else if (L == 2)
            k_select_cp<128><<<gsel, 256, 0, stream>>>(score, y, T64, cnt,
                                                       remap, xout, n, npad, kk);
        else
            k_select_cp_pool<<<gsel, 256, 0, stream>>>(score, y, T64, pmax, psum,
                                                       n, npad, NCH3);

        // ---- fused graph compaction for next layer (ELL, no scans) ----
        if (L == 0)
            k_compact<false><<<(M + TB - 1) / TB, TB, 0, stream>>>(remap, rowptrA, colA,
                                                                   (const int*)nullptr,
                                                                   colEA, degEA, dinv, M);
        else if (L == 1)
            k_compact<true><<<(M + TB - 1) / TB, TB, 0, stream>>>(remap, (const int*)nullptr,
                                                                  colEA, degEA,
                                                                  colEB, degEB, dinv, M);
        else if (L == 2)
            k_compact<true><<<(M + TB - 1) / TB, TB, 0, stream>>>(remap, (const int*)nullptr,
                                                                  colEB, degEB,
                                                                  colEA, degEA, dinv, M);

        M = NB * kk;
        xin = xout;
    }

    k_final2<<<NB, 128, 0, stream>>>(pmax, psum, metadata, convm_w, convm_b,
                                     fc_w, fc_b, fc2_w, fc2_b, (float*)d_out,
                                     Kk[3], NCH3);
}